// Round 15
// baseline (66.166 us; speedup 1.0000x reference)
//
#include <hip/hip_runtime.h>
#include <math.h>

// MAM dense: C[i,j] = max_k(A[i,k]*W[j,k]) + min_k(A[i,k]*W[j,k]) + bias[j]
// A = x flat [M=2048, K=768]; W [N=768, K=768] row-major; out [M,N] f32.
// R14 base (batched forced-asm pk ops, 1-deep kk2 prefetch, dbuf 1-barrier)
// + TM4xTN4 (LDS bytes/product 1.5 -> 1.0) via BM64xBN64 + split-K x2 to keep
// 768 blocks = 3/CU exact. Packed h2{max,min} partials in d_ws (12.6MB),
// streaming combine (~3us). Swizzle scheme proven in R10/R12.

#define M_DIM 2048
#define N_DIM 768
#define K_DIM 768
#define NOUT (M_DIM * N_DIM)   // 1572864

#define BM 64
#define BN 64
#define BK 64
#define KP 32                  // k-pair rows per tile
#define SAH 68                 // A row stride, h2 units
#define SBH 68                 // B row stride, h2 units

typedef _Float16 h2 __attribute__((ext_vector_type(2)));   // 4 B
typedef _Float16 h8 __attribute__((ext_vector_type(8)));   // 16 B

static __device__ __forceinline__ h2 cvt_pk(float x, float y) {
    return __builtin_bit_cast(h2, __builtin_amdgcn_cvt_pkrtz(x, y));
}
// forced single-instruction packed f16 ops
static __device__ __forceinline__ h2 h2mul(h2 a, h2 b) {
    unsigned d;
    asm("v_pk_mul_f16 %0, %1, %2" : "=v"(d)
        : "v"(__builtin_bit_cast(unsigned, a)), "v"(__builtin_bit_cast(unsigned, b)));
    return __builtin_bit_cast(h2, d);
}
static __device__ __forceinline__ h2 h2max(h2 a, h2 b) {
    unsigned d;
    asm("v_pk_max_f16 %0, %1, %2" : "=v"(d)
        : "v"(__builtin_bit_cast(unsigned, a)), "v"(__builtin_bit_cast(unsigned, b)));
    return __builtin_bit_cast(h2, d);
}
static __device__ __forceinline__ h2 h2min(h2 a, h2 b) {
    unsigned d;
    asm("v_pk_min_f16 %0, %1, %2" : "=v"(d)
        : "v"(__builtin_bit_cast(unsigned, a)), "v"(__builtin_bit_cast(unsigned, b)));
    return __builtin_bit_cast(h2, d);
}
static __device__ __forceinline__ unsigned packmm(h2 px, h2 pn) {
    h2 r;
    r.x = px.x >= px.y ? px.x : px.y;   // combined running max
    r.y = pn.x <= pn.y ? pn.x : pn.y;   // combined running min
    return __builtin_bit_cast(unsigned, r);
}

// swizzle: data col c lives at LDS col c ^ (4*((kk2>>1)&7))
#define SWZC(k2) (4 * (((k2) >> 1) & 7))
#define LDA(buf, k2) (*(const h8*)(&As[buf][(k2) * SAH + (am4 ^ SWZC(k2))]))
#define LDB(buf, k2) (*(const h8*)(&Bs[buf][(k2) * SBH + (bn4 ^ SWZC(k2))]))

// one kk2 slice: 2 batches of {8 independent muls -> 8 maxes -> 8 mins}
#define MAMOPS(A_, B_) do {                                                  \
        const h2 am0 = __builtin_shufflevector(A_, A_, 0, 1);                \
        const h2 am1 = __builtin_shufflevector(A_, A_, 2, 3);                \
        const h2 am2 = __builtin_shufflevector(A_, A_, 4, 5);                \
        const h2 am3 = __builtin_shufflevector(A_, A_, 6, 7);                \
        const h2 bn0 = __builtin_shufflevector(B_, B_, 0, 1);                \
        const h2 bn1 = __builtin_shufflevector(B_, B_, 2, 3);                \
        const h2 bn2 = __builtin_shufflevector(B_, B_, 4, 5);                \
        const h2 bn3 = __builtin_shufflevector(B_, B_, 6, 7);                \
        {                                                                    \
            const h2 q0 = h2mul(am0, bn0);                                   \
            const h2 q1 = h2mul(am1, bn0);                                   \
            const h2 q2 = h2mul(am2, bn0);                                   \
            const h2 q3 = h2mul(am3, bn0);                                   \
            const h2 q4 = h2mul(am0, bn1);                                   \
            const h2 q5 = h2mul(am1, bn1);                                   \
            const h2 q6 = h2mul(am2, bn1);                                   \
            const h2 q7 = h2mul(am3, bn1);                                   \
            pmax[0][0] = h2max(pmax[0][0], q0);                              \
            pmax[1][0] = h2max(pmax[1][0], q1);                              \
            pmax[2][0] = h2max(pmax[2][0], q2);                              \
            pmax[3][0] = h2max(pmax[3][0], q3);                              \
            pmax[0][1] = h2max(pmax[0][1], q4);                              \
            pmax[1][1] = h2max(pmax[1][1], q5);                              \
            pmax[2][1] = h2max(pmax[2][1], q6);                              \
            pmax[3][1] = h2max(pmax[3][1], q7);                              \
            pmin[0][0] = h2min(pmin[0][0], q0);                              \
            pmin[1][0] = h2min(pmin[1][0], q1);                              \
            pmin[2][0] = h2min(pmin[2][0], q2);                              \
            pmin[3][0] = h2min(pmin[3][0], q3);                              \
            pmin[0][1] = h2min(pmin[0][1], q4);                              \
            pmin[1][1] = h2min(pmin[1][1], q5);                              \
            pmin[2][1] = h2min(pmin[2][1], q6);                              \
            pmin[3][1] = h2min(pmin[3][1], q7);                              \
        }                                                                    \
        {                                                                    \
            const h2 q0 = h2mul(am0, bn2);                                   \
            const h2 q1 = h2mul(am1, bn2);                                   \
            const h2 q2 = h2mul(am2, bn2);                                   \
            const h2 q3 = h2mul(am3, bn2);                                   \
            const h2 q4 = h2mul(am0, bn3);                                   \
            const h2 q5 = h2mul(am1, bn3);                                   \
            const h2 q6 = h2mul(am2, bn3);                                   \
            const h2 q7 = h2mul(am3, bn3);                                   \
            pmax[0][2] = h2max(pmax[0][2], q0);                              \
            pmax[1][2] = h2max(pmax[1][2], q1);                              \
            pmax[2][2] = h2max(pmax[2][2], q2);                              \
            pmax[3][2] = h2max(pmax[3][2], q3);                              \
            pmax[0][3] = h2max(pmax[0][3], q4);                              \
            pmax[1][3] = h2max(pmax[1][3], q5);                              \
            pmax[2][3] = h2max(pmax[2][3], q6);                              \
            pmax[3][3] = h2max(pmax[3][3], q7);                              \
            pmin[0][2] = h2min(pmin[0][2], q0);                              \
            pmin[1][2] = h2min(pmin[1][2], q1);                              \
            pmin[2][2] = h2min(pmin[2][2], q2);                              \
            pmin[3][2] = h2min(pmin[3][2], q3);                              \
            pmin[0][3] = h2min(pmin[0][3], q4);                              \
            pmin[1][3] = h2min(pmin[1][3], q5);                              \
            pmin[2][3] = h2min(pmin[2][3], q6);                              \
            pmin[3][3] = h2min(pmin[3][3], q7);                              \
        }                                                                    \
    } while (0)

template <int NSPL>
__global__ __launch_bounds__(256, 3) void mam_main(
    const float* __restrict__ A, const float* __restrict__ W,
    const float* __restrict__ bias, float* __restrict__ out,
    unsigned* __restrict__ ws)
{
    __shared__ __align__(16) h2 As[2][KP * SAH];   // 17408 B
    __shared__ __align__(16) h2 Bs[2][KP * SBH];   // 17408 B

    const int tid = threadIdx.x;
    const int m0  = blockIdx.y * BM;
    const int n0  = blockIdx.x * BN;
    const int NT  = 12 / NSPL;                  // k-tiles this block owns
    const int kb  = blockIdx.z * NT * BK;

    const int mt  = tid >> 4;                   // 0..15 -> rows 4mt..4mt+3
    const int nt  = tid & 15;                   // 0..15 -> cols 4nt..4nt+3
    const int am4 = 4 * mt;
    const int bn4 = 4 * nt;

    h2 pmax[4][4], pmin[4][4];
    const _Float16 HMIN = (_Float16)(-65504.0f), HMAX = (_Float16)(65504.0f);
#pragma unroll
    for (int i = 0; i < 4; ++i)
#pragma unroll
        for (int j = 0; j < 4; ++j) {
            pmax[i][j] = (h2){HMIN, HMIN};
            pmin[i][j] = (h2){HMAX, HMAX};
        }

    // staging: thread -> rows arow+{0,16,32,48}, k-chunk akc (kk2 = 2akc,+1)
    const int arow = tid >> 4;                  // 0..15
    const int akc  = tid & 15;
    const int swz  = 4 * (akc & 7);             // matches read-side SWZC
    const float* Ap = A + (size_t)(m0 + arow) * K_DIM + kb + akc * 4;
    const float* Wp = W + (size_t)(n0 + arow) * K_DIM + kb + akc * 4;

    float4 pa0, pa1, pa2, pa3, pb0, pb1, pb2, pb3;

#define GLOAD(t) do {                                                        \
        const float* An_ = Ap + (t) * BK;                                    \
        const float* Wn_ = Wp + (t) * BK;                                    \
        pa0 = *(const float4*)(An_ + (size_t) 0 * K_DIM);                    \
        pa1 = *(const float4*)(An_ + (size_t)16 * K_DIM);                    \
        pa2 = *(const float4*)(An_ + (size_t)32 * K_DIM);                    \
        pa3 = *(const float4*)(An_ + (size_t)48 * K_DIM);                    \
        pb0 = *(const float4*)(Wn_ + (size_t) 0 * K_DIM);                    \
        pb1 = *(const float4*)(Wn_ + (size_t)16 * K_DIM);                    \
        pb2 = *(const float4*)(Wn_ + (size_t)32 * K_DIM);                    \
        pb3 = *(const float4*)(Wn_ + (size_t)48 * K_DIM);                    \
    } while (0)

#define SWRITE(buf) do {                                                     \
        h2* Aw_ = &As[buf][2 * akc * SAH];                                   \
        h2* Bw_ = &Bs[buf][2 * akc * SBH];                                   \
        const int c0_ = (arow +  0) ^ swz;                                   \
        const int c1_ = (arow + 16) ^ swz;                                   \
        const int c2_ = (arow + 32) ^ swz;                                   \
        const int c3_ = (arow + 48) ^ swz;                                   \
        Aw_[c0_]       = cvt_pk(pa0.x, pa0.y);                               \
        Aw_[SAH + c0_] = cvt_pk(pa0.z, pa0.w);                               \
        Aw_[c1_]       = cvt_pk(pa1.x, pa1.y);                               \
        Aw_[SAH + c1_] = cvt_pk(pa1.z, pa1.w);                               \
        Aw_[c2_]       = cvt_pk(pa2.x, pa2.y);                               \
        Aw_[SAH + c2_] = cvt_pk(pa2.z, pa2.w);                               \
        Aw_[c3_]       = cvt_pk(pa3.x, pa3.y);                               \
        Aw_[SAH + c3_] = cvt_pk(pa3.z, pa3.w);                               \
        Bw_[c0_]       = cvt_pk(pb0.x, pb0.y);                               \
        Bw_[SBH + c0_] = cvt_pk(pb0.z, pb0.w);                               \
        Bw_[c1_]       = cvt_pk(pb1.x, pb1.y);                               \
        Bw_[SBH + c1_] = cvt_pk(pb1.z, pb1.w);                               \
        Bw_[c2_]       = cvt_pk(pb2.x, pb2.y);                               \
        Bw_[SBH + c2_] = cvt_pk(pb2.z, pb2.w);                               \
        Bw_[c3_]       = cvt_pk(pb3.x, pb3.y);                               \
        Bw_[SBH + c3_] = cvt_pk(pb3.z, pb3.w);                               \
    } while (0)

    // compute with explicit 1-deep kk2 prefetch (named regs, const offsets)
#define COMPUTE(buf) do {                                                    \
        h8 cA_ = LDA(buf, 0), cB_ = LDB(buf, 0);                             \
        _Pragma("unroll")                                                    \
        for (int kk2 = 0; kk2 < KP - 1; ++kk2) {                             \
            const h8 nA_ = LDA(buf, kk2 + 1);                                \
            const h8 nB_ = LDB(buf, kk2 + 1);                                \
            MAMOPS(cA_, cB_);                                                \
            cA_ = nA_; cB_ = nB_;                                            \
        }                                                                    \
        MAMOPS(cA_, cB_);                                                    \
    } while (0)

    // prologue: tile 0 -> buf 0
    GLOAD(0);
    SWRITE(0);
    __syncthreads();

    // dbuf main loop, one barrier per tile (NT even: 6 or 12)
#pragma unroll 1
    for (int ktt = 0; ktt < NT / 2 - 1; ++ktt) {
        GLOAD(2 * ktt + 1);        // issue early: latency hides under compute
        COMPUTE(0);
        SWRITE(1);                 // write late: loads have landed
        __syncthreads();
        GLOAD(2 * ktt + 2);
        COMPUTE(1);
        SWRITE(0);
        __syncthreads();
    }
    GLOAD(NT - 1);
    COMPUTE(0);
    SWRITE(1);
    __syncthreads();
    COMPUTE(1);

    if (NSPL == 1) {
        const float4 bv = *(const float4*)(bias + n0 + bn4);
#pragma unroll
        for (int i = 0; i < 4; ++i) {
            float4 o;
            o.x = fmaxf((float)pmax[i][0].x, (float)pmax[i][0].y)
                + fminf((float)pmin[i][0].x, (float)pmin[i][0].y) + bv.x;
            o.y = fmaxf((float)pmax[i][1].x, (float)pmax[i][1].y)
                + fminf((float)pmin[i][1].x, (float)pmin[i][1].y) + bv.y;
            o.z = fmaxf((float)pmax[i][2].x, (float)pmax[i][2].y)
                + fminf((float)pmin[i][2].x, (float)pmin[i][2].y) + bv.z;
            o.w = fmaxf((float)pmax[i][3].x, (float)pmax[i][3].y)
                + fminf((float)pmin[i][3].x, (float)pmin[i][3].y) + bv.w;
            *(float4*)&out[(size_t)(m0 + am4 + i) * N_DIM + n0 + bn4] = o;
        }
    } else {
        unsigned* wp = ws + (size_t)blockIdx.z * NOUT
                          + (size_t)(m0 + am4) * N_DIM + n0 + bn4;
#pragma unroll
        for (int i = 0; i < 4; ++i) {
            uint4 v;
            v.x = packmm(pmax[i][0], pmin[i][0]);
            v.y = packmm(pmax[i][1], pmin[i][1]);
            v.z = packmm(pmax[i][2], pmin[i][2]);
            v.w = packmm(pmax[i][3], pmin[i][3]);
            *(uint4*)(wp + (size_t)i * N_DIM) = v;
        }
    }
}

// combine (2-way): out = max(maxes) + min(mins) + bias; ~19 MB streaming
__global__ __launch_bounds__(256) void mam_combine2(
    const unsigned* __restrict__ ws, const float* __restrict__ bias,
    float* __restrict__ out)
{
    const int i4 = (blockIdx.x * 256 + threadIdx.x) * 4;
    const uint4 v0 = *(const uint4*)(ws + i4);
    const uint4 v1 = *(const uint4*)(ws + (size_t)NOUT + i4);
    const float4 bv = *(const float4*)(bias + (i4 % N_DIM));
    float4 o;
#define CMB(e) do {                                                          \
        const h2 a_ = __builtin_bit_cast(h2, v0.e);                          \
        const h2 b_ = __builtin_bit_cast(h2, v1.e);                          \
        const h2 mx_ = h2max(a_, b_);                                        \
        const h2 mn_ = h2min(a_, b_);                                        \
        o.e = (float)mx_.x + (float)mn_.y + bv.e;                            \
    } while (0)
    CMB(x); CMB(y); CMB(z); CMB(w);
#undef CMB
    *(float4*)(out + i4) = o;
}

extern "C" void kernel_launch(void* const* d_in, const int* in_sizes, int n_in,
                              void* d_out, int out_size, void* d_ws, size_t ws_size,
                              hipStream_t stream) {
    const float* x    = (const float*)d_in[0];   // [2,1024,768] -> [2048,768]
    const float* w    = (const float*)d_in[1];   // [768,768] row-major [N][K]
    const float* bias = (const float*)d_in[2];   // [768]
    float* out = (float*)d_out;                  // [2048,768]

    const size_t need2 = (size_t)2 * NOUT * sizeof(unsigned);   // 12.6 MB
    if (ws_size >= need2) {
        // split-K x2: (12,32,2) = 768 blocks = 3/CU exact
        mam_main<2><<<dim3(N_DIM / BN, M_DIM / BM, 2), 256, 0, stream>>>(
            x, w, bias, out, (unsigned*)d_ws);
        mam_combine2<<<NOUT / 4 / 256, 256, 0, stream>>>(
            (const unsigned*)d_ws, bias, out);
    } else {
        // fallback: single kernel, 384 blocks (imbalanced but correct)
        mam_main<1><<<dim3(N_DIM / BN, M_DIM / BM, 1), 256, 0, stream>>>(
            x, w, bias, out, nullptr);
    }
}

// Round 16
// 62.835 us; speedup vs baseline: 1.0530x; 1.0530x over previous
//
#include <hip/hip_runtime.h>
#include <math.h>

// MAM dense: C[i,j] = max_k(A[i,k]*W[j,k]) + min_k(A[i,k]*W[j,k]) + bias[j]
// A = x flat [M=2048, K=768]; W [N=768, K=768] row-major; out [M,N] f32.
// R14 winner (single kernel, BM64xBN32, TM4xTN2, 768 blocks = 3/CU, dbuf,
// batched forced-asm pk ops) + paired-kk2 compute: 16 independent pk_muls ->
// 16 maxes -> 16 mins per pair, with 2-deep LDS prefetch (fully covers ~120cy
// LDS latency under ~200cy of independent compute). Instruction count is at
// the algebraic floor (3 pk ops / 2 products); measured VALU rate ~4.15
// cyc/wave-instr across all op classes -> busy floor ~47us; this round
// targets the remaining ~15us of stall exposure.

#define M_DIM 2048
#define N_DIM 768
#define K_DIM 768

#define BM 64
#define BN 32
#define BK 64
#define KP (BK / 2)            // 32 k-pair rows per tile
#define NTILES (K_DIM / BK)    // 12

// LDS strides in h2 (4B) units (R8/R14-proven layout).
#define SAH 68                 // A: b128 read 16B-aligned, 16-way broadcast
#define SBH 34                 // B: b64 read, banks spread

typedef _Float16 h2 __attribute__((ext_vector_type(2)));   // 4 B
typedef _Float16 h4 __attribute__((ext_vector_type(4)));   // 8 B
typedef _Float16 h8 __attribute__((ext_vector_type(8)));   // 16 B

static __device__ __forceinline__ h2 cvt_pk(float x, float y) {
    return __builtin_bit_cast(h2, __builtin_amdgcn_cvt_pkrtz(x, y));
}
// forced single-instruction packed f16 ops
static __device__ __forceinline__ h2 h2mul(h2 a, h2 b) {
    unsigned d;
    asm("v_pk_mul_f16 %0, %1, %2" : "=v"(d)
        : "v"(__builtin_bit_cast(unsigned, a)), "v"(__builtin_bit_cast(unsigned, b)));
    return __builtin_bit_cast(h2, d);
}
static __device__ __forceinline__ h2 h2max(h2 a, h2 b) {
    unsigned d;
    asm("v_pk_max_f16 %0, %1, %2" : "=v"(d)
        : "v"(__builtin_bit_cast(unsigned, a)), "v"(__builtin_bit_cast(unsigned, b)));
    return __builtin_bit_cast(h2, d);
}
static __device__ __forceinline__ h2 h2min(h2 a, h2 b) {
    unsigned d;
    asm("v_pk_min_f16 %0, %1, %2" : "=v"(d)
        : "v"(__builtin_bit_cast(unsigned, a)), "v"(__builtin_bit_cast(unsigned, b)));
    return __builtin_bit_cast(h2, d);
}

// paired-kk2 slice: 16 independent muls, then 16 max-updates, then 16 mins.
// (X_,Y_ = kk2 and kk2+1 operands; accumulators shared, chains spaced 16 ops)
#define MAMOPS2(AX_, BX_, AY_, BY_) do {                                     \
        const h2 xa0 = __builtin_shufflevector(AX_, AX_, 0, 1);              \
        const h2 xa1 = __builtin_shufflevector(AX_, AX_, 2, 3);              \
        const h2 xa2 = __builtin_shufflevector(AX_, AX_, 4, 5);              \
        const h2 xa3 = __builtin_shufflevector(AX_, AX_, 6, 7);              \
        const h2 xb0 = __builtin_shufflevector(BX_, BX_, 0, 1);              \
        const h2 xb1 = __builtin_shufflevector(BX_, BX_, 2, 3);              \
        const h2 ya0 = __builtin_shufflevector(AY_, AY_, 0, 1);              \
        const h2 ya1 = __builtin_shufflevector(AY_, AY_, 2, 3);              \
        const h2 ya2 = __builtin_shufflevector(AY_, AY_, 4, 5);              \
        const h2 ya3 = __builtin_shufflevector(AY_, AY_, 6, 7);              \
        const h2 yb0 = __builtin_shufflevector(BY_, BY_, 0, 1);              \
        const h2 yb1 = __builtin_shufflevector(BY_, BY_, 2, 3);              \
        const h2 q0  = h2mul(xa0, xb0);                                      \
        const h2 q1  = h2mul(xa1, xb0);                                      \
        const h2 q2  = h2mul(xa2, xb0);                                      \
        const h2 q3  = h2mul(xa3, xb0);                                      \
        const h2 q4  = h2mul(xa0, xb1);                                      \
        const h2 q5  = h2mul(xa1, xb1);                                      \
        const h2 q6  = h2mul(xa2, xb1);                                      \
        const h2 q7  = h2mul(xa3, xb1);                                      \
        const h2 r0  = h2mul(ya0, yb0);                                      \
        const h2 r1  = h2mul(ya1, yb0);                                      \
        const h2 r2  = h2mul(ya2, yb0);                                      \
        const h2 r3  = h2mul(ya3, yb0);                                      \
        const h2 r4  = h2mul(ya0, yb1);                                      \
        const h2 r5  = h2mul(ya1, yb1);                                      \
        const h2 r6  = h2mul(ya2, yb1);                                      \
        const h2 r7  = h2mul(ya3, yb1);                                      \
        pmax[0][0] = h2max(pmax[0][0], q0);                                  \
        pmax[1][0] = h2max(pmax[1][0], q1);                                  \
        pmax[2][0] = h2max(pmax[2][0], q2);                                  \
        pmax[3][0] = h2max(pmax[3][0], q3);                                  \
        pmax[0][1] = h2max(pmax[0][1], q4);                                  \
        pmax[1][1] = h2max(pmax[1][1], q5);                                  \
        pmax[2][1] = h2max(pmax[2][1], q6);                                  \
        pmax[3][1] = h2max(pmax[3][1], q7);                                  \
        pmax[0][0] = h2max(pmax[0][0], r0);                                  \
        pmax[1][0] = h2max(pmax[1][0], r1);                                  \
        pmax[2][0] = h2max(pmax[2][0], r2);                                  \
        pmax[3][0] = h2max(pmax[3][0], r3);                                  \
        pmax[0][1] = h2max(pmax[0][1], r4);                                  \
        pmax[1][1] = h2max(pmax[1][1], r5);                                  \
        pmax[2][1] = h2max(pmax[2][1], r6);                                  \
        pmax[3][1] = h2max(pmax[3][1], r7);                                  \
        pmin[0][0] = h2min(pmin[0][0], q0);                                  \
        pmin[1][0] = h2min(pmin[1][0], q1);                                  \
        pmin[2][0] = h2min(pmin[2][0], q2);                                  \
        pmin[3][0] = h2min(pmin[3][0], q3);                                  \
        pmin[0][1] = h2min(pmin[0][1], q4);                                  \
        pmin[1][1] = h2min(pmin[1][1], q5);                                  \
        pmin[2][1] = h2min(pmin[2][1], q6);                                  \
        pmin[3][1] = h2min(pmin[3][1], q7);                                  \
        pmin[0][0] = h2min(pmin[0][0], r0);                                  \
        pmin[1][0] = h2min(pmin[1][0], r1);                                  \
        pmin[2][0] = h2min(pmin[2][0], r2);                                  \
        pmin[3][0] = h2min(pmin[3][0], r3);                                  \
        pmin[0][1] = h2min(pmin[0][1], r4);                                  \
        pmin[1][1] = h2min(pmin[1][1], r5);                                  \
        pmin[2][1] = h2min(pmin[2][1], r6);                                  \
        pmin[3][1] = h2min(pmin[3][1], r7);                                  \
    } while (0)

__global__ __launch_bounds__(256, 3) void mam_kernel(
    const float* __restrict__ A, const float* __restrict__ W,
    const float* __restrict__ bias, float* __restrict__ out)
{
    __shared__ __align__(16) h2 As[2][KP * SAH];
    __shared__ __align__(16) h2 Bs[2][KP * SBH];

    const int tid = threadIdx.x;
    const int m0 = blockIdx.y * BM;
    const int n0 = blockIdx.x * BN;
    const int mt = tid >> 4;   // 0..15 -> rows mt*4..mt*4+3
    const int nt = tid & 15;   // 0..15 -> cols nt*2..nt*2+1

    h2 pmax[4][2], pmin[4][2];
    const _Float16 HMIN = (_Float16)(-65504.0f), HMAX = (_Float16)(65504.0f);
#pragma unroll
    for (int i = 0; i < 4; ++i)
#pragma unroll
        for (int j = 0; j < 2; ++j) {
            pmax[i][j] = (h2){HMIN, HMIN};
            pmin[i][j] = (h2){HMAX, HMAX};
        }

    // staging map: thread -> rows arow+16q, k-chunk akc (kk2 = 2akc, 2akc+1)
    const int arow = tid >> 4;
    const int akc  = tid & 15;
    const float* Ap = A + (size_t)(m0 + arow) * K_DIM + akc * 4;
    const float* Wp = W + (size_t)(n0 + arow) * K_DIM + akc * 4;

    const float bb0 = bias[n0 + nt * 2 + 0];
    const float bb1 = bias[n0 + nt * 2 + 1];

    float4 pa0, pa1, pa2, pa3, pb0, pb1;

#define GLOAD(t) do {                                                        \
        const float* An_ = Ap + (t) * BK;                                    \
        const float* Wn_ = Wp + (t) * BK;                                    \
        pa0 = *(const float4*)(An_ + (size_t) 0 * K_DIM);                    \
        pa1 = *(const float4*)(An_ + (size_t)16 * K_DIM);                    \
        pa2 = *(const float4*)(An_ + (size_t)32 * K_DIM);                    \
        pa3 = *(const float4*)(An_ + (size_t)48 * K_DIM);                    \
        pb0 = *(const float4*)(Wn_ + (size_t) 0 * K_DIM);                    \
        pb1 = *(const float4*)(Wn_ + (size_t)16 * K_DIM);                    \
    } while (0)

#define SWRITE(buf) do {                                                     \
        h2* Aw_ = &As[buf][2 * akc * SAH + arow];                            \
        Aw_[0]        = cvt_pk(pa0.x, pa0.y);                                \
        Aw_[SAH]      = cvt_pk(pa0.z, pa0.w);                                \
        Aw_[16]       = cvt_pk(pa1.x, pa1.y);                                \
        Aw_[SAH + 16] = cvt_pk(pa1.z, pa1.w);                                \
        Aw_[32]       = cvt_pk(pa2.x, pa2.y);                                \
        Aw_[SAH + 32] = cvt_pk(pa2.z, pa2.w);                                \
        Aw_[48]       = cvt_pk(pa3.x, pa3.y);                                \
        Aw_[SAH + 48] = cvt_pk(pa3.z, pa3.w);                                \
        h2* Bw_ = &Bs[buf][2 * akc * SBH + arow];                            \
        Bw_[0]        = cvt_pk(pb0.x, pb0.y);                                \
        Bw_[SBH]      = cvt_pk(pb0.z, pb0.w);                                \
        Bw_[16]       = cvt_pk(pb1.x, pb1.y);                                \
        Bw_[SBH + 16] = cvt_pk(pb1.z, pb1.w);                                \
    } while (0)

    // paired compute with 2-deep LDS prefetch (named regs, const offsets)
#define COMPUTE(buf) do {                                                    \
        const h2* Ab_ = &As[buf][mt * 4];                                    \
        const h2* Bb_ = &Bs[buf][nt * 2];                                    \
        h8 cA0_ = *(const h8*)(Ab_);                                         \
        h4 cB0_ = *(const h4*)(Bb_);                                         \
        h8 cA1_ = *(const h8*)(Ab_ + SAH);                                   \
        h4 cB1_ = *(const h4*)(Bb_ + SBH);                                   \
        _Pragma("unroll")                                                    \
        for (int kp_ = 0; kp_ < KP / 2 - 1; ++kp_) {                         \
            const h8 nA0_ = *(const h8*)(Ab_ + (2 * kp_ + 2) * SAH);         \
            const h4 nB0_ = *(const h4*)(Bb_ + (2 * kp_ + 2) * SBH);         \
            const h8 nA1_ = *(const h8*)(Ab_ + (2 * kp_ + 3) * SAH);         \
            const h4 nB1_ = *(const h4*)(Bb_ + (2 * kp_ + 3) * SBH);         \
            MAMOPS2(cA0_, cB0_, cA1_, cB1_);                                 \
            cA0_ = nA0_; cB0_ = nB0_; cA1_ = nA1_; cB1_ = nB1_;              \
        }                                                                    \
        MAMOPS2(cA0_, cB0_, cA1_, cB1_);                                     \
    } while (0)

    // prologue: tile 0 -> buf 0
    GLOAD(0);
    SWRITE(0);
    __syncthreads();

    // dbuf main loop, one barrier per tile
#pragma unroll 1
    for (int ktt = 0; ktt < NTILES / 2 - 1; ++ktt) {
        GLOAD(2 * ktt + 1);        // issue early: latency hides under compute
        COMPUTE(0);
        SWRITE(1);                 // write late: loads have landed
        __syncthreads();
        GLOAD(2 * ktt + 2);
        COMPUTE(1);
        SWRITE(0);
        __syncthreads();
    }
    // peeled tail
    GLOAD(NTILES - 1);
    COMPUTE(0);
    SWRITE(1);
    __syncthreads();
    COMPUTE(1);

    // epilogue: combine even/odd extrema, add bias, store f32
#pragma unroll
    for (int i = 0; i < 4; ++i) {
        float2 o;
        o.x = fmaxf((float)pmax[i][0].x, (float)pmax[i][0].y)
            + fminf((float)pmin[i][0].x, (float)pmin[i][0].y) + bb0;
        o.y = fmaxf((float)pmax[i][1].x, (float)pmax[i][1].y)
            + fminf((float)pmin[i][1].x, (float)pmin[i][1].y) + bb1;
        *(float2*)&out[(size_t)(m0 + mt * 4 + i) * N_DIM + n0 + nt * 2] = o;
    }
}

extern "C" void kernel_launch(void* const* d_in, const int* in_sizes, int n_in,
                              void* d_out, int out_size, void* d_ws, size_t ws_size,
                              hipStream_t stream) {
    const float* x    = (const float*)d_in[0];   // [2,1024,768] -> [2048,768]
    const float* w    = (const float*)d_in[1];   // [768,768] row-major [N][K]
    const float* bias = (const float*)d_in[2];   // [768]
    float* out = (float*)d_out;                  // [2048,768]

    dim3 grid(N_DIM / BN, M_DIM / BM);           // (24, 32) = 768 blocks = 3/CU
    mam_kernel<<<grid, 256, 0, stream>>>(x, w, bias, out);
}